// Round 10
// baseline (197.995 us; speedup 1.0000x reference)
//
#include <hip/hip_runtime.h>
#include <math.h>

#define NB 4
#define DD 128
#define HH 128
#define WW 128
#define VOX (DD*HH*WW)          // 2097152 = 2^21
#define NVOX (NB*VOX)           // 8388608

struct GaussW { float w[7]; };
struct CurlIn { float4 wc, wyn, vc, vzn, uc, uzn, uyn; float wxp, vxp; };

__device__ __forceinline__ float4 f4zero() { float4 z; z.x = z.y = z.z = z.w = 0.f; return z; }

// ---------------------------------------------------------------------------
// R0-verbatim dual kernel (best measured: 63.7-66.0 us). R6/R7 async-LDS
// restructures raised occupancy (40->54%) and VALUBusy (24->48%) but REGRESSED
// dur (65 -> 68.5 -> 71 us): the structure absorbs concurrency into overhead.
// Reverting to the leanest (register-staged) variant.
__device__ __forceinline__ CurlIn curl4_load(const float* __restrict__ u,
                                             const float* __restrict__ vv,
                                             const float* __restrict__ w,
                                             int z, int y, int x0) {
    int xq = x0 >> 2;
    size_t s = ((size_t)z << 14) | ((size_t)y << 7) | (size_t)x0;
    int dy = (y < 127) ? 128 : -128;
    int dz = (z < 127) ? 16384 : -16384;
    int dxp = (xq < 31) ? 4 : 0;
    CurlIn ci;
    ci.wc  = *(const float4*)(w  + s);
    ci.wyn = *(const float4*)(w  + s + dy);
    ci.vc  = *(const float4*)(vv + s);
    ci.vzn = *(const float4*)(vv + s + dz);
    ci.uc  = *(const float4*)(u  + s);
    ci.uzn = *(const float4*)(u  + s + dz);
    ci.uyn = *(const float4*)(u  + s + dy);
    ci.wxp = w [s + 3 + dxp];
    ci.vxp = vv[s + 3 + dxp];
    return ci;
}

__device__ __forceinline__ float4 curl4_math(const CurlIn& ci, int z, int y, int x0) {
    float sy = (y < 127) ? 1.f : -1.f;
    float sz = (z < 127) ? 1.f : -1.f;
    float wca[4] = {ci.wc.x, ci.wc.y, ci.wc.z, ci.wc.w};
    float vca[4] = {ci.vc.x, ci.vc.y, ci.vc.z, ci.vc.w};
    float wya[4] = {ci.wyn.x, ci.wyn.y, ci.wyn.z, ci.wyn.w};
    float vza[4] = {ci.vzn.x, ci.vzn.y, ci.vzn.z, ci.vzn.w};
    float uca[4] = {ci.uc.x, ci.uc.y, ci.uc.z, ci.uc.w};
    float uza[4] = {ci.uzn.x, ci.uzn.y, ci.uzn.z, ci.uzn.w};
    float uya[4] = {ci.uyn.x, ci.uyn.y, ci.uyn.z, ci.uyn.w};
    float wsh[4] = {ci.wc.y, ci.wc.z, ci.wc.w, ci.wxp};
    float vsh[4] = {ci.vc.y, ci.vc.z, ci.vc.w, ci.vxp};

    float4 o;
    float* oa = &o.x;
#pragma unroll
    for (int j = 0; j < 4; ++j) {
        int x = x0 + j;
        float fdxw = (x < 127) ? (wsh[j] - wca[j]) : (wca[3] - wca[2]);
        float fdxv = (x < 127) ? (vsh[j] - vca[j]) : (vca[3] - vca[2]);
        float fdyw = sy * (wya[j] - wca[j]);
        float fdyu = sy * (uya[j] - uca[j]);
        float fdzv = sz * (vza[j] - vca[j]);
        float fdzu = sz * (uza[j] - uca[j]);
        float cu = fdyw - fdzv;
        float cv = fdzu - fdxw;
        float cw = fdxv - fdyu;
        oa[j] = sqrtf(cu * cu + cv * cv + cw * cw);
    }
    return o;
}

__global__ __launch_bounds__(512, 2)
void yx_curl_dual_kernel(const float* __restrict__ dIn, float* __restrict__ P,
                         const float* __restrict__ v,   float* __restrict__ Q,
                         GaussW gw) {
    __shared__ float in_t[38][128];    // rows y0-3 .. y0+34 (19456 B)

    const int NT = 512;
    int bb = blockIdx.x;               // 4096
    bool isCurl = (bb >= 2048);
    int b  = bb & 2047;
    int yq = b & 3;
    int z  = (b >> 2) & 127;
    int n  = b >> 9;
    int y0 = yq * 32;
    size_t slice = (((size_t)n << 7) | (size_t)z) << 14;
    int tid = threadIdx.x;

    if (!isCurl) {
        float4 Ld[3];
#pragma unroll
        for (int t = 0; t < 3; ++t) {          // phase 1: all loads
            int j  = tid + t * NT;
            int r  = j >> 5;
            int c4 = (j & 31) << 2;
            int gy = y0 - 3 + r;
            Ld[t] = (j < 1216 && gy >= 0 && gy < 128)
                  ? *(const float4*)(dIn + slice + ((size_t)gy << 7) + c4)
                  : f4zero();
        }
#pragma unroll
        for (int t = 0; t < 3; ++t) {          // phase 2: LDS writes
            int j = tid + t * NT;
            if (j < 1216) *(float4*)&in_t[j >> 5][(j & 31) << 2] = Ld[t];
        }
    } else {
        const float* u  = v + (size_t)n * 3 * VOX;
        const float* vv = u + VOX;
        const float* w  = vv + VOX;
        CurlIn ci[3];
        bool inb[3];
#pragma unroll
        for (int t = 0; t < 3; ++t) {          // phase 1: burst-issue all loads
            int j  = tid + t * NT;
            int r  = j >> 5;
            int c4 = (j & 31) << 2;
            int gy = y0 - 3 + r;
            inb[t] = (j < 1216 && gy >= 0 && gy < 128);
            if (inb[t]) ci[t] = curl4_load(u, vv, w, z, gy, c4);
        }
#pragma unroll
        for (int t = 0; t < 3; ++t) {          // phase 2: math + LDS writes
            int j  = tid + t * NT;
            if (j < 1216) {
                int r  = j >> 5;
                int c4 = (j & 31) << 2;
                int gy = y0 - 3 + r;
                float4 val = inb[t] ? curl4_math(ci[t], z, gy, c4) : f4zero();
                *(float4*)&in_t[r][c4] = val;
            }
        }
    }
    __syncthreads();

    // y-conv into registers (2 float4 per thread covering the 32x32 float4 grid)
    float4 rr[2];
#pragma unroll
    for (int t = 0; t < 2; ++t) {
        int j  = tid + t * NT;
        int yo = j >> 5;
        int c4 = (j & 31) << 2;
        float4 a = f4zero();
#pragma unroll
        for (int k = 0; k < 7; ++k) {
            float wk = gw.w[k];
            float4 tv = *(const float4*)&in_t[yo + k][c4];
            a.x += wk * tv.x; a.y += wk * tv.y; a.z += wk * tv.z; a.w += wk * tv.w;
        }
        rr[t] = a;
    }
    __syncthreads();

    // write y-conv results back into in_t rows 0..31 (reuse as mid)
#pragma unroll
    for (int t = 0; t < 2; ++t) {
        int j  = tid + t * NT;
        *(float4*)&in_t[j >> 5][(j & 31) << 2] = rr[t];
    }
    __syncthreads();

    // x-conv -> global, zero-pad at x edges via guarded loads
    float* out = isCurl ? Q : P;
#pragma unroll
    for (int t = 0; t < 2; ++t) {
        int j   = tid + t * NT;
        int yo  = j >> 5;
        int x0c = (j & 31) << 2;
        float4 q0 = (x0c > 0)   ? *(const float4*)&in_t[yo][x0c - 4] : f4zero();
        float4 q1 =               *(const float4*)&in_t[yo][x0c];
        float4 q2 = (x0c < 124) ? *(const float4*)&in_t[yo][x0c + 4] : f4zero();
        float wdw[11] = {q0.y, q0.z, q0.w,
                         q1.x, q1.y, q1.z, q1.w,
                         q2.x, q2.y, q2.z, q2.w};
        float o[4];
#pragma unroll
        for (int j2 = 0; j2 < 4; ++j2) {
            float acc = 0.f;
#pragma unroll
            for (int k = 0; k < 7; ++k) acc += gw.w[k] * wdw[j2 + k];
            o[j2] = acc;
        }
        *(float4*)(out + slice + ((size_t)(y0 + yo) << 7) + x0c) =
            make_float4(o[0], o[1], o[2], o[3]);
    }
}

// ---------------------------------------------------------------------------
// Render, LDS-staged. OLD: 77 scattered global loads/thread at 16-64KB stride
// (z-columns) -> suspected latency-bound. NEW: block = 64 columns (one x-half
// of one (n,y)); cooperatively stage the whole 128-z slab of P and Q into LDS
// (2 x 32KB, coalesced 256B bursts, 16 independent float4 loads in flight per
// thread), then identical scan math reads LDS (2-way bank aliasing = free).
__global__ __launch_bounds__(256, 2)
void render_lds_kernel(const float* __restrict__ P, const float* __restrict__ Q,
                       float* __restrict__ out, GaussW gw) {
    __shared__ float Pl[128][64];      // 32768 B  [z][x-within-half]
    __shared__ float Ql[128][64];      // 32768 B
    __shared__ float csum[4][64];
    __shared__ float part[4][64];

    int tid = threadIdx.x;
    int bid = blockIdx.x;              // 1024 = 4n * 128y * 2xh
    int col0 = bid << 6;
    int n  = col0 >> 14;
    int y  = (col0 >> 7) & 127;
    int x0 = col0 & 64;                // 0 or 64
    size_t base = ((size_t)n << 21) | ((size_t)y << 7) | (size_t)x0;

    // ---- stage: 8 rounds x 16 z-planes; 16 threads x float4 per plane ----
    int zrow = tid >> 4;               // 0..15
    int xq   = (tid & 15) << 2;        // 0,4,..,60
#pragma unroll
    for (int r = 0; r < 8; ++r) {
        int zi = (r << 4) + zrow;
        size_t off = base + ((size_t)zi << 14) + xq;
        *(float4*)&Pl[zi][xq] = *(const float4*)(P + off);
        *(float4*)&Ql[zi][xq] = *(const float4*)(Q + off);
    }
    __syncthreads();

    int xl = tid & 63;
    int ch = tid >> 6;
    int j0 = ch * 32;

    // z-smooth of flipped P for this chunk (identical math, LDS source)
    float a[38];
#pragma unroll
    for (int t = 0; t < 38; ++t) {
        int j = j0 - 3 + t;
        a[t] = (j >= 0 && j <= 127) ? Pl[127 - j][xl] : 0.f;
    }
#pragma unroll
    for (int i = 0; i < 32; ++i) {
        float s = 0.f;
#pragma unroll
        for (int k = 0; k < 7; ++k) s += gw.w[k] * a[i + k];
        a[i] = s;
    }
    float S = 0.f;
#pragma unroll
    for (int i = 0; i < 32; ++i) S += a[i];
    csum[ch][xl] = S;
    __syncthreads();

    float offset = 0.f;
    if (ch > 0) offset += csum[0][xl];
    if (ch > 1) offset += csum[1][xl];
    if (ch > 2) offset += csum[2][xl];

    float tp = 0.f, vp = 0.f, acc = 0.f, xacc = offset;
    if (ch > 0) {
        float v0 = 0.f;
#pragma unroll
        for (int k = 0; k < 7; ++k) {          // vnf[j0-1]: j = j0-4+k, all in range
            int j = j0 - 4 + k;
            v0 += gw.w[k] * Ql[127 - j][xl];
        }
        vp = v0;
        float xc = 20.f * offset;
        tp = (xc + 1.f) * __expf(-xc);
    }
#pragma unroll
    for (int i = 0; i < 32; ++i) {
        xacc += a[i];
        float vk = 0.f;
#pragma unroll
        for (int k = 0; k < 7; ++k) {          // vnf[j0+i]: j = j0+i-3+k
            int j = j0 + i - 3 + k;
            float qv = (j >= 0 && j <= 127) ? Ql[127 - j][xl] : 0.f;
            vk += gw.w[k] * qv;
        }
        float xc = 20.f * xacc;
        float tk = (xc + 1.f) * __expf(-xc);
        if (ch == 0 && i == 0) acc = (1.f - tk) * vk;
        else                   acc += (tp - tk) * (vp + vk) * 0.5f;
        tp = tk; vp = vk;
    }
    part[ch][xl] = acc;
    __syncthreads();

    if (ch == 0) {
        float r = part[0][xl] + part[1][xl] + part[2][xl] + part[3][xl];
        out[col0 + xl] = fminf(fmaxf(r, 0.f), 1.f);
    }
}

// ---------------------------------------------------------------------------
extern "C" void kernel_launch(void* const* d_in, const int* in_sizes, int n_in,
                              void* d_out, int out_size, void* d_ws, size_t ws_size,
                              hipStream_t stream) {
    const float* d = (const float*)d_in[0];   // (4,1,128,128,128)
    const float* v = (const float*)d_in[1];   // (4,3,128,128,128)
    float* out = (float*)d_out;               // (4,1,128,128)

    GaussW gw;
    {
        double g[7], s = 0.0;
        for (int i = 0; i < 7; ++i) {
            double t = (i - 3) / 1.6;
            g[i] = exp(-t * t / 2.0);
            s += g[i];
        }
        for (int i = 0; i < 7; ++i) gw.w[i] = (float)(g[i] / s);
    }

    float* ws0 = (float*)d_ws;        // P = yx-smoothed d
    float* ws1 = ws0 + NVOX;          // Q = yx-smoothed |curl|

    // 1) fused: d yx-smooth (blocks 0-2047) + curl-on-the-fly yx-smooth (2048-4095)
    yx_curl_dual_kernel<<<2 * NB * DD * 4, 512, 0, stream>>>(d, ws0, v, ws1, gw);

    // 2) render: LDS-staged column slabs + scan + on-the-fly z-smooth
    render_lds_kernel<<<(NB * HH * WW) / 64, 256, 0, stream>>>(ws0, ws1, out, gw);
}

// Round 11
// 195.702 us; speedup vs baseline: 1.0117x; 1.0117x over previous
//
#include <hip/hip_runtime.h>
#include <math.h>

#define NB 4
#define DD 128
#define HH 128
#define WW 128
#define VOX (DD*HH*WW)          // 2097152 = 2^21
#define NVOX (NB*VOX)           // 8388608

struct GaussW { float w[7]; };
struct CurlIn { float4 wc, wyn, vc, vzn, uc, uzn, uyn; float wxp, vxp; };

__device__ __forceinline__ float4 f4zero() { float4 z; z.x = z.y = z.z = z.w = 0.f; return z; }

// ---------------------------------------------------------------------------
// R0-verbatim dual kernel (best measured: 63.7-68.5 us across R0/R10).
// R6/R7 async-LDS restructures raised occupancy (40->54%) and VALUBusy
// (24->48%) but REGRESSED dur (65 -> 68.5 -> 71): concurrency was absorbed
// by overhead work. This register-staged variant is the measured optimum.
__device__ __forceinline__ CurlIn curl4_load(const float* __restrict__ u,
                                             const float* __restrict__ vv,
                                             const float* __restrict__ w,
                                             int z, int y, int x0) {
    int xq = x0 >> 2;
    size_t s = ((size_t)z << 14) | ((size_t)y << 7) | (size_t)x0;
    int dy = (y < 127) ? 128 : -128;
    int dz = (z < 127) ? 16384 : -16384;
    int dxp = (xq < 31) ? 4 : 0;
    CurlIn ci;
    ci.wc  = *(const float4*)(w  + s);
    ci.wyn = *(const float4*)(w  + s + dy);
    ci.vc  = *(const float4*)(vv + s);
    ci.vzn = *(const float4*)(vv + s + dz);
    ci.uc  = *(const float4*)(u  + s);
    ci.uzn = *(const float4*)(u  + s + dz);
    ci.uyn = *(const float4*)(u  + s + dy);
    ci.wxp = w [s + 3 + dxp];
    ci.vxp = vv[s + 3 + dxp];
    return ci;
}

__device__ __forceinline__ float4 curl4_math(const CurlIn& ci, int z, int y, int x0) {
    float sy = (y < 127) ? 1.f : -1.f;
    float sz = (z < 127) ? 1.f : -1.f;
    float wca[4] = {ci.wc.x, ci.wc.y, ci.wc.z, ci.wc.w};
    float vca[4] = {ci.vc.x, ci.vc.y, ci.vc.z, ci.vc.w};
    float wya[4] = {ci.wyn.x, ci.wyn.y, ci.wyn.z, ci.wyn.w};
    float vza[4] = {ci.vzn.x, ci.vzn.y, ci.vzn.z, ci.vzn.w};
    float uca[4] = {ci.uc.x, ci.uc.y, ci.uc.z, ci.uc.w};
    float uza[4] = {ci.uzn.x, ci.uzn.y, ci.uzn.z, ci.uzn.w};
    float uya[4] = {ci.uyn.x, ci.uyn.y, ci.uyn.z, ci.uyn.w};
    float wsh[4] = {ci.wc.y, ci.wc.z, ci.wc.w, ci.wxp};
    float vsh[4] = {ci.vc.y, ci.vc.z, ci.vc.w, ci.vxp};

    float4 o;
    float* oa = &o.x;
#pragma unroll
    for (int j = 0; j < 4; ++j) {
        int x = x0 + j;
        float fdxw = (x < 127) ? (wsh[j] - wca[j]) : (wca[3] - wca[2]);
        float fdxv = (x < 127) ? (vsh[j] - vca[j]) : (vca[3] - vca[2]);
        float fdyw = sy * (wya[j] - wca[j]);
        float fdyu = sy * (uya[j] - uca[j]);
        float fdzv = sz * (vza[j] - vca[j]);
        float fdzu = sz * (uza[j] - uca[j]);
        float cu = fdyw - fdzv;
        float cv = fdzu - fdxw;
        float cw = fdxv - fdyu;
        oa[j] = sqrtf(cu * cu + cv * cv + cw * cw);
    }
    return o;
}

__global__ __launch_bounds__(512, 2)
void yx_curl_dual_kernel(const float* __restrict__ dIn, float* __restrict__ P,
                         const float* __restrict__ v,   float* __restrict__ Q,
                         GaussW gw) {
    __shared__ float in_t[38][128];    // rows y0-3 .. y0+34 (19456 B)

    const int NT = 512;
    int bb = blockIdx.x;               // 4096
    bool isCurl = (bb >= 2048);
    int b  = bb & 2047;
    int yq = b & 3;
    int z  = (b >> 2) & 127;
    int n  = b >> 9;
    int y0 = yq * 32;
    size_t slice = (((size_t)n << 7) | (size_t)z) << 14;
    int tid = threadIdx.x;

    if (!isCurl) {
        float4 Ld[3];
#pragma unroll
        for (int t = 0; t < 3; ++t) {          // phase 1: all loads
            int j  = tid + t * NT;
            int r  = j >> 5;
            int c4 = (j & 31) << 2;
            int gy = y0 - 3 + r;
            Ld[t] = (j < 1216 && gy >= 0 && gy < 128)
                  ? *(const float4*)(dIn + slice + ((size_t)gy << 7) + c4)
                  : f4zero();
        }
#pragma unroll
        for (int t = 0; t < 3; ++t) {          // phase 2: LDS writes
            int j = tid + t * NT;
            if (j < 1216) *(float4*)&in_t[j >> 5][(j & 31) << 2] = Ld[t];
        }
    } else {
        const float* u  = v + (size_t)n * 3 * VOX;
        const float* vv = u + VOX;
        const float* w  = vv + VOX;
        CurlIn ci[3];
        bool inb[3];
#pragma unroll
        for (int t = 0; t < 3; ++t) {          // phase 1: burst-issue all loads
            int j  = tid + t * NT;
            int r  = j >> 5;
            int c4 = (j & 31) << 2;
            int gy = y0 - 3 + r;
            inb[t] = (j < 1216 && gy >= 0 && gy < 128);
            if (inb[t]) ci[t] = curl4_load(u, vv, w, z, gy, c4);
        }
#pragma unroll
        for (int t = 0; t < 3; ++t) {          // phase 2: math + LDS writes
            int j  = tid + t * NT;
            if (j < 1216) {
                int r  = j >> 5;
                int c4 = (j & 31) << 2;
                int gy = y0 - 3 + r;
                float4 val = inb[t] ? curl4_math(ci[t], z, gy, c4) : f4zero();
                *(float4*)&in_t[r][c4] = val;
            }
        }
    }
    __syncthreads();

    // y-conv into registers (2 float4 per thread covering the 32x32 float4 grid)
    float4 rr[2];
#pragma unroll
    for (int t = 0; t < 2; ++t) {
        int j  = tid + t * NT;
        int yo = j >> 5;
        int c4 = (j & 31) << 2;
        float4 a = f4zero();
#pragma unroll
        for (int k = 0; k < 7; ++k) {
            float wk = gw.w[k];
            float4 tv = *(const float4*)&in_t[yo + k][c4];
            a.x += wk * tv.x; a.y += wk * tv.y; a.z += wk * tv.z; a.w += wk * tv.w;
        }
        rr[t] = a;
    }
    __syncthreads();

    // write y-conv results back into in_t rows 0..31 (reuse as mid)
#pragma unroll
    for (int t = 0; t < 2; ++t) {
        int j  = tid + t * NT;
        *(float4*)&in_t[j >> 5][(j & 31) << 2] = rr[t];
    }
    __syncthreads();

    // x-conv -> global, zero-pad at x edges via guarded loads
    float* out = isCurl ? Q : P;
#pragma unroll
    for (int t = 0; t < 2; ++t) {
        int j   = tid + t * NT;
        int yo  = j >> 5;
        int x0c = (j & 31) << 2;
        float4 q0 = (x0c > 0)   ? *(const float4*)&in_t[yo][x0c - 4] : f4zero();
        float4 q1 =               *(const float4*)&in_t[yo][x0c];
        float4 q2 = (x0c < 124) ? *(const float4*)&in_t[yo][x0c + 4] : f4zero();
        float wdw[11] = {q0.y, q0.z, q0.w,
                         q1.x, q1.y, q1.z, q1.w,
                         q2.x, q2.y, q2.z, q2.w};
        float o[4];
#pragma unroll
        for (int j2 = 0; j2 < 4; ++j2) {
            float acc = 0.f;
#pragma unroll
            for (int k = 0; k < 7; ++k) acc += gw.w[k] * wdw[j2 + k];
            o[j2] = acc;
        }
        *(float4*)(out + slice + ((size_t)(y0 + yo) << 7) + x0c) =
            make_float4(o[0], o[1], o[2], o[3]);
    }
}

// ---------------------------------------------------------------------------
// Render v3: 512 threads, 8 z-chunks of 16 (serial scan halved vs 4x32),
// single 32KB LDS buffer reused P->Q so LDS = 36KB -> all 4 blocks/CU of the
// 1024-block grid co-resident. P/Q (64MB) are L3-resident after kernel 1, so
// the two staging passes are cheap coalesced reads.
__global__ __launch_bounds__(512, 2)
void render_z8_kernel(const float* __restrict__ P, const float* __restrict__ Q,
                      float* __restrict__ out, GaussW gw) {
    __shared__ float Buf[128][64];     // 32768 B, staged P then Q
    __shared__ float csum[8][64];      // 2048 B
    __shared__ float part[8][64];      // 2048 B

    int tid = threadIdx.x;
    int bid = blockIdx.x;              // 1024 = 4n * 128y * 2xh
    int col0 = bid << 6;
    int n  = col0 >> 14;
    int y  = (col0 >> 7) & 127;
    int x0 = col0 & 64;                // 0 or 64
    size_t base = ((size_t)n << 21) | ((size_t)y << 7) | (size_t)x0;

    int zrow = tid >> 4;               // 0..31
    int xq   = (tid & 15) << 2;        // 0,4,..,60

    // ---- stage P: 4 rounds x 32 z-planes, 1 float4/thread/round ----
#pragma unroll
    for (int r = 0; r < 4; ++r) {
        int zi = (r << 5) + zrow;
        *(float4*)&Buf[zi][xq] = *(const float4*)(P + base + ((size_t)zi << 14) + xq);
    }
    __syncthreads();

    int xl = tid & 63;
    int ch = tid >> 6;                 // 0..7
    int j0 = ch << 4;                  // 16 flipped-z outputs per chunk

    // z-smooth of flipped P for this chunk (zero-padded window)
    float a[22];
#pragma unroll
    for (int t = 0; t < 22; ++t) {
        int j = j0 - 3 + t;
        a[t] = (j >= 0 && j <= 127) ? Buf[127 - j][xl] : 0.f;
    }
#pragma unroll
    for (int i = 0; i < 16; ++i) {
        float s = 0.f;
#pragma unroll
        for (int k = 0; k < 7; ++k) s += gw.w[k] * a[i + k];
        a[i] = s;
    }
    float S = 0.f;
#pragma unroll
    for (int i = 0; i < 16; ++i) S += a[i];
    csum[ch][xl] = S;
    __syncthreads();                   // P reads done; csum visible

    // ---- stage Q over the same buffer; overlap offset math with loads ----
#pragma unroll
    for (int r = 0; r < 4; ++r) {
        int zi = (r << 5) + zrow;
        *(float4*)&Buf[zi][xq] = *(const float4*)(Q + base + ((size_t)zi << 14) + xq);
    }
    float offset = 0.f;
#pragma unroll
    for (int c = 0; c < 7; ++c) if (ch > c) offset += csum[c][xl];
    __syncthreads();

    float tp = 0.f, vp = 0.f, acc = 0.f, xacc = offset;
    if (ch > 0) {
        float v0 = 0.f;
#pragma unroll
        for (int k = 0; k < 7; ++k) {          // vnf[j0-1]: j = j0-4+k >= 12, in range
            int j = j0 - 4 + k;
            v0 += gw.w[k] * Buf[127 - j][xl];
        }
        vp = v0;
        float xc = 20.f * offset;
        tp = (xc + 1.f) * __expf(-xc);
    }
#pragma unroll
    for (int i = 0; i < 16; ++i) {
        xacc += a[i];
        float vk = 0.f;
#pragma unroll
        for (int k = 0; k < 7; ++k) {          // vnf[j0+i]: j = j0+i-3+k
            int j = j0 + i - 3 + k;
            float qv = (j >= 0 && j <= 127) ? Buf[127 - j][xl] : 0.f;
            vk += gw.w[k] * qv;
        }
        float xc = 20.f * xacc;
        float tk = (xc + 1.f) * __expf(-xc);
        if (ch == 0 && i == 0) acc = (1.f - tk) * vk;
        else                   acc += (tp - tk) * (vp + vk) * 0.5f;
        tp = tk; vp = vk;
    }
    part[ch][xl] = acc;
    __syncthreads();

    if (ch == 0) {
        float r = part[0][xl] + part[1][xl] + part[2][xl] + part[3][xl]
                + part[4][xl] + part[5][xl] + part[6][xl] + part[7][xl];
        out[col0 + xl] = fminf(fmaxf(r, 0.f), 1.f);
    }
}

// ---------------------------------------------------------------------------
extern "C" void kernel_launch(void* const* d_in, const int* in_sizes, int n_in,
                              void* d_out, int out_size, void* d_ws, size_t ws_size,
                              hipStream_t stream) {
    const float* d = (const float*)d_in[0];   // (4,1,128,128,128)
    const float* v = (const float*)d_in[1];   // (4,3,128,128,128)
    float* out = (float*)d_out;               // (4,1,128,128)

    GaussW gw;
    {
        double g[7], s = 0.0;
        for (int i = 0; i < 7; ++i) {
            double t = (i - 3) / 1.6;
            g[i] = exp(-t * t / 2.0);
            s += g[i];
        }
        for (int i = 0; i < 7; ++i) gw.w[i] = (float)(g[i] / s);
    }

    float* ws0 = (float*)d_ws;        // P = yx-smoothed d
    float* ws1 = ws0 + NVOX;          // Q = yx-smoothed |curl|

    // 1) fused: d yx-smooth (blocks 0-2047) + curl-on-the-fly yx-smooth (2048-4095)
    yx_curl_dual_kernel<<<2 * NB * DD * 4, 512, 0, stream>>>(d, ws0, v, ws1, gw);

    // 2) render: 8-way z-chunk scan, single reused LDS buffer
    render_z8_kernel<<<(NB * HH * WW) / 64, 512, 0, stream>>>(ws0, ws1, out, gw);
}

// Round 12
// 194.399 us; speedup vs baseline: 1.0185x; 1.0067x over previous
//
#include <hip/hip_runtime.h>
#include <math.h>

#define NB 4
#define DD 128
#define HH 128
#define WW 128
#define VOX (DD*HH*WW)          // 2097152 = 2^21
#define NVOX (NB*VOX)           // 8388608

struct GaussW { float w[7]; };
struct CurlIn { float4 wc, wyn, vc, vzn, uc, uzn, uyn; float wxp, vxp; };

__device__ __forceinline__ float4 f4zero() { float4 z; z.x = z.y = z.z = z.w = 0.f; return z; }

// ---------------------------------------------------------------------------
// Dual kernel v4 = R0 structure with BRANCHLESS staging loads.
// R0/R10/R11 measured 62-68 us at VGPR=56: the 27-float4 curl burst
// (needs ~114 result VGPRs) was serialized into ~3 dependent latency rounds.
// R6/R7 (LDS staging) regressed; the guards `if(inb[t])` around the loads are
// the remaining suspect - hipcc won't batch loads across divergent branches.
// v4 clamps indices and loads unconditionally (dup loads are cache-hot),
// zeroing at the consume/write step. launch_bounds(512,2) allows 128 VGPR.
__device__ __forceinline__ CurlIn curl4_load(const float* __restrict__ u,
                                             const float* __restrict__ vv,
                                             const float* __restrict__ w,
                                             int z, int y, int x0) {
    int xq = x0 >> 2;
    size_t s = ((size_t)z << 14) | ((size_t)y << 7) | (size_t)x0;
    int dy = (y < 127) ? 128 : -128;
    int dz = (z < 127) ? 16384 : -16384;
    int dxp = (xq < 31) ? 4 : 0;
    CurlIn ci;
    ci.wc  = *(const float4*)(w  + s);
    ci.wyn = *(const float4*)(w  + s + dy);
    ci.vc  = *(const float4*)(vv + s);
    ci.vzn = *(const float4*)(vv + s + dz);
    ci.uc  = *(const float4*)(u  + s);
    ci.uzn = *(const float4*)(u  + s + dz);
    ci.uyn = *(const float4*)(u  + s + dy);
    ci.wxp = w [s + 3 + dxp];
    ci.vxp = vv[s + 3 + dxp];
    return ci;
}

__device__ __forceinline__ float4 curl4_math(const CurlIn& ci, int z, int y, int x0) {
    float sy = (y < 127) ? 1.f : -1.f;
    float sz = (z < 127) ? 1.f : -1.f;
    float wca[4] = {ci.wc.x, ci.wc.y, ci.wc.z, ci.wc.w};
    float vca[4] = {ci.vc.x, ci.vc.y, ci.vc.z, ci.vc.w};
    float wya[4] = {ci.wyn.x, ci.wyn.y, ci.wyn.z, ci.wyn.w};
    float vza[4] = {ci.vzn.x, ci.vzn.y, ci.vzn.z, ci.vzn.w};
    float uca[4] = {ci.uc.x, ci.uc.y, ci.uc.z, ci.uc.w};
    float uza[4] = {ci.uzn.x, ci.uzn.y, ci.uzn.z, ci.uzn.w};
    float uya[4] = {ci.uyn.x, ci.uyn.y, ci.uyn.z, ci.uyn.w};
    float wsh[4] = {ci.wc.y, ci.wc.z, ci.wc.w, ci.wxp};
    float vsh[4] = {ci.vc.y, ci.vc.z, ci.vc.w, ci.vxp};

    float4 o;
    float* oa = &o.x;
#pragma unroll
    for (int j = 0; j < 4; ++j) {
        int x = x0 + j;
        float fdxw = (x < 127) ? (wsh[j] - wca[j]) : (wca[3] - wca[2]);
        float fdxv = (x < 127) ? (vsh[j] - vca[j]) : (vca[3] - vca[2]);
        float fdyw = sy * (wya[j] - wca[j]);
        float fdyu = sy * (uya[j] - uca[j]);
        float fdzv = sz * (vza[j] - vca[j]);
        float fdzu = sz * (uza[j] - uca[j]);
        float cu = fdyw - fdzv;
        float cv = fdzu - fdxw;
        float cw = fdxv - fdyu;
        oa[j] = sqrtf(cu * cu + cv * cv + cw * cw);
    }
    return o;
}

__global__ __launch_bounds__(512, 2)
void yx_curl_dual_kernel(const float* __restrict__ dIn, float* __restrict__ P,
                         const float* __restrict__ v,   float* __restrict__ Q,
                         GaussW gw) {
    __shared__ float in_t[38][128];    // rows y0-3 .. y0+34 (19456 B)

    const int NT = 512;
    int bb = blockIdx.x;               // 4096
    bool isCurl = (bb >= 2048);
    int b  = bb & 2047;
    int yq = b & 3;
    int z  = (b >> 2) & 127;
    int n  = b >> 9;
    int y0 = yq * 32;
    size_t slice = (((size_t)n << 7) | (size_t)z) << 14;
    int tid = threadIdx.x;

    if (!isCurl) {
        float4 Ld[3];
        bool inb[3];
#pragma unroll
        for (int t = 0; t < 3; ++t) {          // phase 1: unconditional loads
            int j  = tid + t * NT;
            int jj = (j < 1216) ? j : 1215;    // clamp: dup item 1215 (cache-hot)
            int r  = jj >> 5;
            int c4 = (jj & 31) << 2;
            int gy = y0 - 3 + r;
            inb[t] = (j < 1216 && gy >= 0 && gy < 128);
            int gc = min(127, max(0, gy));
            Ld[t] = *(const float4*)(dIn + slice + ((size_t)gc << 7) + c4);
        }
#pragma unroll
        for (int t = 0; t < 3; ++t) {          // phase 2: LDS writes (zero halo)
            int j = tid + t * NT;
            if (j < 1216)
                *(float4*)&in_t[j >> 5][(j & 31) << 2] = inb[t] ? Ld[t] : f4zero();
        }
    } else {
        const float* u  = v + (size_t)n * 3 * VOX;
        const float* vv = u + VOX;
        const float* w  = vv + VOX;
        CurlIn ci[3];
        bool inb[3];
#pragma unroll
        for (int t = 0; t < 3; ++t) {          // phase 1: branchless burst issue
            int j  = tid + t * NT;
            int jj = (j < 1216) ? j : 1215;
            int r  = jj >> 5;
            int c4 = (jj & 31) << 2;
            int gy = y0 - 3 + r;
            inb[t] = (j < 1216 && gy >= 0 && gy < 128);
            int gc = min(127, max(0, gy));
            ci[t] = curl4_load(u, vv, w, z, gc, c4);
        }
#pragma unroll
        for (int t = 0; t < 3; ++t) {          // phase 2: math + LDS writes
            int j  = tid + t * NT;
            if (j < 1216) {
                int r  = j >> 5;
                int c4 = (j & 31) << 2;
                int gy = y0 - 3 + r;
                float4 val = inb[t] ? curl4_math(ci[t], z, gy, c4) : f4zero();
                *(float4*)&in_t[r][c4] = val;
            }
        }
    }
    __syncthreads();

    // y-conv into registers (2 float4 per thread covering the 32x32 float4 grid)
    float4 rr[2];
#pragma unroll
    for (int t = 0; t < 2; ++t) {
        int j  = tid + t * NT;
        int yo = j >> 5;
        int c4 = (j & 31) << 2;
        float4 a = f4zero();
#pragma unroll
        for (int k = 0; k < 7; ++k) {
            float wk = gw.w[k];
            float4 tv = *(const float4*)&in_t[yo + k][c4];
            a.x += wk * tv.x; a.y += wk * tv.y; a.z += wk * tv.z; a.w += wk * tv.w;
        }
        rr[t] = a;
    }
    __syncthreads();

    // write y-conv results back into in_t rows 0..31 (reuse as mid)
#pragma unroll
    for (int t = 0; t < 2; ++t) {
        int j  = tid + t * NT;
        *(float4*)&in_t[j >> 5][(j & 31) << 2] = rr[t];
    }
    __syncthreads();

    // x-conv -> global, zero-pad at x edges via guarded loads
    float* out = isCurl ? Q : P;
#pragma unroll
    for (int t = 0; t < 2; ++t) {
        int j   = tid + t * NT;
        int yo  = j >> 5;
        int x0c = (j & 31) << 2;
        float4 q0 = (x0c > 0)   ? *(const float4*)&in_t[yo][x0c - 4] : f4zero();
        float4 q1 =               *(const float4*)&in_t[yo][x0c];
        float4 q2 = (x0c < 124) ? *(const float4*)&in_t[yo][x0c + 4] : f4zero();
        float wdw[11] = {q0.y, q0.z, q0.w,
                         q1.x, q1.y, q1.z, q1.w,
                         q2.x, q2.y, q2.z, q2.w};
        float o[4];
#pragma unroll
        for (int j2 = 0; j2 < 4; ++j2) {
            float acc = 0.f;
#pragma unroll
            for (int k = 0; k < 7; ++k) acc += gw.w[k] * wdw[j2 + k];
            o[j2] = acc;
        }
        *(float4*)(out + slice + ((size_t)(y0 + yo) << 7) + x0c) =
            make_float4(o[0], o[1], o[2], o[3]);
    }
}

// ---------------------------------------------------------------------------
// Render v3 (R11, measured best total): 512 threads, 8 z-chunks of 16,
// single 32KB LDS buffer reused P->Q (36KB total -> 4 blocks/CU co-resident).
__global__ __launch_bounds__(512, 2)
void render_z8_kernel(const float* __restrict__ P, const float* __restrict__ Q,
                      float* __restrict__ out, GaussW gw) {
    __shared__ float Buf[128][64];     // 32768 B, staged P then Q
    __shared__ float csum[8][64];      // 2048 B
    __shared__ float part[8][64];      // 2048 B

    int tid = threadIdx.x;
    int bid = blockIdx.x;              // 1024 = 4n * 128y * 2xh
    int col0 = bid << 6;
    int n  = col0 >> 14;
    int y  = (col0 >> 7) & 127;
    int x0 = col0 & 64;                // 0 or 64
    size_t base = ((size_t)n << 21) | ((size_t)y << 7) | (size_t)x0;

    int zrow = tid >> 4;               // 0..31
    int xq   = (tid & 15) << 2;        // 0,4,..,60

    // ---- stage P: 4 rounds x 32 z-planes, 1 float4/thread/round ----
#pragma unroll
    for (int r = 0; r < 4; ++r) {
        int zi = (r << 5) + zrow;
        *(float4*)&Buf[zi][xq] = *(const float4*)(P + base + ((size_t)zi << 14) + xq);
    }
    __syncthreads();

    int xl = tid & 63;
    int ch = tid >> 6;                 // 0..7
    int j0 = ch << 4;                  // 16 flipped-z outputs per chunk

    // z-smooth of flipped P for this chunk (zero-padded window)
    float a[22];
#pragma unroll
    for (int t = 0; t < 22; ++t) {
        int j = j0 - 3 + t;
        a[t] = (j >= 0 && j <= 127) ? Buf[127 - j][xl] : 0.f;
    }
#pragma unroll
    for (int i = 0; i < 16; ++i) {
        float s = 0.f;
#pragma unroll
        for (int k = 0; k < 7; ++k) s += gw.w[k] * a[i + k];
        a[i] = s;
    }
    float S = 0.f;
#pragma unroll
    for (int i = 0; i < 16; ++i) S += a[i];
    csum[ch][xl] = S;
    __syncthreads();                   // P reads done; csum visible

    // ---- stage Q over the same buffer; overlap offset math with loads ----
#pragma unroll
    for (int r = 0; r < 4; ++r) {
        int zi = (r << 5) + zrow;
        *(float4*)&Buf[zi][xq] = *(const float4*)(Q + base + ((size_t)zi << 14) + xq);
    }
    float offset = 0.f;
#pragma unroll
    for (int c = 0; c < 7; ++c) if (ch > c) offset += csum[c][xl];
    __syncthreads();

    float tp = 0.f, vp = 0.f, acc = 0.f, xacc = offset;
    if (ch > 0) {
        float v0 = 0.f;
#pragma unroll
        for (int k = 0; k < 7; ++k) {          // vnf[j0-1]: j = j0-4+k >= 12, in range
            int j = j0 - 4 + k;
            v0 += gw.w[k] * Buf[127 - j][xl];
        }
        vp = v0;
        float xc = 20.f * offset;
        tp = (xc + 1.f) * __expf(-xc);
    }
#pragma unroll
    for (int i = 0; i < 16; ++i) {
        xacc += a[i];
        float vk = 0.f;
#pragma unroll
        for (int k = 0; k < 7; ++k) {          // vnf[j0+i]: j = j0+i-3+k
            int j = j0 + i - 3 + k;
            float qv = (j >= 0 && j <= 127) ? Buf[127 - j][xl] : 0.f;
            vk += gw.w[k] * qv;
        }
        float xc = 20.f * xacc;
        float tk = (xc + 1.f) * __expf(-xc);
        if (ch == 0 && i == 0) acc = (1.f - tk) * vk;
        else                   acc += (tp - tk) * (vp + vk) * 0.5f;
        tp = tk; vp = vk;
    }
    part[ch][xl] = acc;
    __syncthreads();

    if (ch == 0) {
        float r = part[0][xl] + part[1][xl] + part[2][xl] + part[3][xl]
                + part[4][xl] + part[5][xl] + part[6][xl] + part[7][xl];
        out[col0 + xl] = fminf(fmaxf(r, 0.f), 1.f);
    }
}

// ---------------------------------------------------------------------------
extern "C" void kernel_launch(void* const* d_in, const int* in_sizes, int n_in,
                              void* d_out, int out_size, void* d_ws, size_t ws_size,
                              hipStream_t stream) {
    const float* d = (const float*)d_in[0];   // (4,1,128,128,128)
    const float* v = (const float*)d_in[1];   // (4,3,128,128,128)
    float* out = (float*)d_out;               // (4,1,128,128)

    GaussW gw;
    {
        double g[7], s = 0.0;
        for (int i = 0; i < 7; ++i) {
            double t = (i - 3) / 1.6;
            g[i] = exp(-t * t / 2.0);
            s += g[i];
        }
        for (int i = 0; i < 7; ++i) gw.w[i] = (float)(g[i] / s);
    }

    float* ws0 = (float*)d_ws;        // P = yx-smoothed d
    float* ws1 = ws0 + NVOX;          // Q = yx-smoothed |curl|

    // 1) fused: d yx-smooth (blocks 0-2047) + curl-on-the-fly yx-smooth (2048-4095)
    yx_curl_dual_kernel<<<2 * NB * DD * 4, 512, 0, stream>>>(d, ws0, v, ws1, gw);

    // 2) render: 8-way z-chunk scan, single reused LDS buffer
    render_z8_kernel<<<(NB * HH * WW) / 64, 512, 0, stream>>>(ws0, ws1, out, gw);
}

// Round 14
// 192.380 us; speedup vs baseline: 1.0292x; 1.0105x over previous
//
#include <hip/hip_runtime.h>
#include <math.h>

#define NB 4
#define DD 128
#define HH 128
#define WW 128
#define VOX (DD*HH*WW)          // 2097152 = 2^21
#define NVOX (NB*VOX)           // 8388608

struct GaussW { float w[7]; };
struct CurlIn { float4 wc, wyn, vc, vzn, uc, uzn, uyn; float wxp, vxp; };

__device__ __forceinline__ float4 f4zero() { float4 z; z.x = z.y = z.z = z.w = 0.f; return z; }

// ---------------------------------------------------------------------------
// Dual kernel: R0 structure, branchless staging loads (R12; 63.4-64.6 us,
// VGPR 60). Five structural variants (register burst, async-LDS 16/8-row,
// branchless) all land in 62-71 us with both pipes <40% — a compiler/latency
// structural plateau. This is the best-of-band variant.
__device__ __forceinline__ CurlIn curl4_load(const float* __restrict__ u,
                                             const float* __restrict__ vv,
                                             const float* __restrict__ w,
                                             int z, int y, int x0) {
    int xq = x0 >> 2;
    size_t s = ((size_t)z << 14) | ((size_t)y << 7) | (size_t)x0;
    int dy = (y < 127) ? 128 : -128;
    int dz = (z < 127) ? 16384 : -16384;
    int dxp = (xq < 31) ? 4 : 0;
    CurlIn ci;
    ci.wc  = *(const float4*)(w  + s);
    ci.wyn = *(const float4*)(w  + s + dy);
    ci.vc  = *(const float4*)(vv + s);
    ci.vzn = *(const float4*)(vv + s + dz);
    ci.uc  = *(const float4*)(u  + s);
    ci.uzn = *(const float4*)(u  + s + dz);
    ci.uyn = *(const float4*)(u  + s + dy);
    ci.wxp = w [s + 3 + dxp];
    ci.vxp = vv[s + 3 + dxp];
    return ci;
}

__device__ __forceinline__ float4 curl4_math(const CurlIn& ci, int z, int y, int x0) {
    float sy = (y < 127) ? 1.f : -1.f;
    float sz = (z < 127) ? 1.f : -1.f;
    float wca[4] = {ci.wc.x, ci.wc.y, ci.wc.z, ci.wc.w};
    float vca[4] = {ci.vc.x, ci.vc.y, ci.vc.z, ci.vc.w};
    float wya[4] = {ci.wyn.x, ci.wyn.y, ci.wyn.z, ci.wyn.w};
    float vza[4] = {ci.vzn.x, ci.vzn.y, ci.vzn.z, ci.vzn.w};
    float uca[4] = {ci.uc.x, ci.uc.y, ci.uc.z, ci.uc.w};
    float uza[4] = {ci.uzn.x, ci.uzn.y, ci.uzn.z, ci.uzn.w};
    float uya[4] = {ci.uyn.x, ci.uyn.y, ci.uyn.z, ci.uyn.w};
    float wsh[4] = {ci.wc.y, ci.wc.z, ci.wc.w, ci.wxp};
    float vsh[4] = {ci.vc.y, ci.vc.z, ci.vc.w, ci.vxp};

    float4 o;
    float* oa = &o.x;
#pragma unroll
    for (int j = 0; j < 4; ++j) {
        int x = x0 + j;
        float fdxw = (x < 127) ? (wsh[j] - wca[j]) : (wca[3] - wca[2]);
        float fdxv = (x < 127) ? (vsh[j] - vca[j]) : (vca[3] - vca[2]);
        float fdyw = sy * (wya[j] - wca[j]);
        float fdyu = sy * (uya[j] - uca[j]);
        float fdzv = sz * (vza[j] - vca[j]);
        float fdzu = sz * (uza[j] - uca[j]);
        float cu = fdyw - fdzv;
        float cv = fdzu - fdxw;
        float cw = fdxv - fdyu;
        oa[j] = sqrtf(cu * cu + cv * cv + cw * cw);
    }
    return o;
}

__global__ __launch_bounds__(512, 2)
void yx_curl_dual_kernel(const float* __restrict__ dIn, float* __restrict__ P,
                         const float* __restrict__ v,   float* __restrict__ Q,
                         GaussW gw) {
    __shared__ float in_t[38][128];    // rows y0-3 .. y0+34 (19456 B)

    const int NT = 512;
    int bb = blockIdx.x;               // 4096
    bool isCurl = (bb >= 2048);
    int b  = bb & 2047;
    int yq = b & 3;
    int z  = (b >> 2) & 127;
    int n  = b >> 9;
    int y0 = yq * 32;
    size_t slice = (((size_t)n << 7) | (size_t)z) << 14;
    int tid = threadIdx.x;

    if (!isCurl) {
        float4 Ld[3];
        bool inb[3];
#pragma unroll
        for (int t = 0; t < 3; ++t) {          // phase 1: unconditional loads
            int j  = tid + t * NT;
            int jj = (j < 1216) ? j : 1215;    // clamp: dup item 1215 (cache-hot)
            int r  = jj >> 5;
            int c4 = (jj & 31) << 2;
            int gy = y0 - 3 + r;
            inb[t] = (j < 1216 && gy >= 0 && gy < 128);
            int gc = min(127, max(0, gy));
            Ld[t] = *(const float4*)(dIn + slice + ((size_t)gc << 7) + c4);
        }
#pragma unroll
        for (int t = 0; t < 3; ++t) {          // phase 2: LDS writes (zero halo)
            int j = tid + t * NT;
            if (j < 1216)
                *(float4*)&in_t[j >> 5][(j & 31) << 2] = inb[t] ? Ld[t] : f4zero();
        }
    } else {
        const float* u  = v + (size_t)n * 3 * VOX;
        const float* vv = u + VOX;
        const float* w  = vv + VOX;
        CurlIn ci[3];
        bool inb[3];
#pragma unroll
        for (int t = 0; t < 3; ++t) {          // phase 1: branchless burst issue
            int j  = tid + t * NT;
            int jj = (j < 1216) ? j : 1215;
            int r  = jj >> 5;
            int c4 = (jj & 31) << 2;
            int gy = y0 - 3 + r;
            inb[t] = (j < 1216 && gy >= 0 && gy < 128);
            int gc = min(127, max(0, gy));
            ci[t] = curl4_load(u, vv, w, z, gc, c4);
        }
#pragma unroll
        for (int t = 0; t < 3; ++t) {          // phase 2: math + LDS writes
            int j  = tid + t * NT;
            if (j < 1216) {
                int r  = j >> 5;
                int c4 = (j & 31) << 2;
                int gy = y0 - 3 + r;
                float4 val = inb[t] ? curl4_math(ci[t], z, gy, c4) : f4zero();
                *(float4*)&in_t[r][c4] = val;
            }
        }
    }
    __syncthreads();

    // y-conv into registers (2 float4 per thread covering the 32x32 float4 grid)
    float4 rr[2];
#pragma unroll
    for (int t = 0; t < 2; ++t) {
        int j  = tid + t * NT;
        int yo = j >> 5;
        int c4 = (j & 31) << 2;
        float4 a = f4zero();
#pragma unroll
        for (int k = 0; k < 7; ++k) {
            float wk = gw.w[k];
            float4 tv = *(const float4*)&in_t[yo + k][c4];
            a.x += wk * tv.x; a.y += wk * tv.y; a.z += wk * tv.z; a.w += wk * tv.w;
        }
        rr[t] = a;
    }
    __syncthreads();

    // write y-conv results back into in_t rows 0..31 (reuse as mid)
#pragma unroll
    for (int t = 0; t < 2; ++t) {
        int j  = tid + t * NT;
        *(float4*)&in_t[j >> 5][(j & 31) << 2] = rr[t];
    }
    __syncthreads();

    // x-conv -> global, zero-pad at x edges via guarded loads
    float* out = isCurl ? Q : P;
#pragma unroll
    for (int t = 0; t < 2; ++t) {
        int j   = tid + t * NT;
        int yo  = j >> 5;
        int x0c = (j & 31) << 2;
        float4 q0 = (x0c > 0)   ? *(const float4*)&in_t[yo][x0c - 4] : f4zero();
        float4 q1 =               *(const float4*)&in_t[yo][x0c];
        float4 q2 = (x0c < 124) ? *(const float4*)&in_t[yo][x0c + 4] : f4zero();
        float wdw[11] = {q0.y, q0.z, q0.w,
                         q1.x, q1.y, q1.z, q1.w,
                         q2.x, q2.y, q2.z, q2.w};
        float o[4];
#pragma unroll
        for (int j2 = 0; j2 < 4; ++j2) {
            float acc = 0.f;
#pragma unroll
            for (int k = 0; k < 7; ++k) acc += gw.w[k] * wdw[j2 + k];
            o[j2] = acc;
        }
        *(float4*)(out + slice + ((size_t)(y0 + yo) << 7) + x0c) =
            make_float4(o[0], o[1], o[2], o[3]);
    }
}

// ---------------------------------------------------------------------------
// Render: R0-verbatim render_zs4 (accompanied the best measured total, 191.8).
// Its 77 z-plane reads per thread are wave-coalesced 256B bursts on L3-hot
// P/Q; LDS-staged rewrites (v2: 198.0, v3: 195.7) were neutral-to-negative.
__global__ __launch_bounds__(256, 4)
void render_zs4_kernel(const float* __restrict__ P, const float* __restrict__ Q,
                       float* __restrict__ out, GaussW gw) {
    __shared__ float csum[4][64];
    __shared__ float part[4][64];

    int xl = threadIdx.x & 63;
    int ch = threadIdx.x >> 6;
    int col = blockIdx.x * 64 + xl;       // 1024 blocks * 64 = 65536 columns
    int x = col & 127;
    int y = (col >> 7) & 127;
    int n = col >> 14;
    size_t volbase = ((size_t)n << 21) | ((size_t)y << 7) | (size_t)x;
    int j0 = ch * 32;

    float a[38];
#pragma unroll
    for (int t = 0; t < 38; ++t) {
        int j = j0 - 3 + t;
        a[t] = (j >= 0 && j <= 127) ? P[volbase + ((size_t)(127 - j) << 14)] : 0.f;
    }
#pragma unroll
    for (int i = 0; i < 32; ++i) {
        float s = 0.f;
#pragma unroll
        for (int k = 0; k < 7; ++k) s += gw.w[k] * a[i + k];
        a[i] = s;
    }
    float S = 0.f;
#pragma unroll
    for (int i = 0; i < 32; ++i) S += a[i];
    csum[ch][xl] = S;

    float bq[39];
#pragma unroll
    for (int t = 0; t < 39; ++t) {
        int j = j0 - 4 + t;
        bq[t] = (j >= 0 && j <= 127) ? Q[volbase + ((size_t)(127 - j) << 14)] : 0.f;
    }
    __syncthreads();

    float offset = 0.f;
    if (ch > 0) offset += csum[0][xl];
    if (ch > 1) offset += csum[1][xl];
    if (ch > 2) offset += csum[2][xl];

    float tp = 0.f, vp = 0.f, acc = 0.f, xacc = offset;
    if (ch > 0) {
        float v0 = 0.f;
#pragma unroll
        for (int k = 0; k < 7; ++k) v0 += gw.w[k] * bq[k];   // vnf[j0-1]
        vp = v0;
        float xc = 20.f * offset;
        tp = (xc + 1.f) * __expf(-xc);
    }
#pragma unroll
    for (int i = 0; i < 32; ++i) {
        xacc += a[i];
        float vk = 0.f;
#pragma unroll
        for (int k = 0; k < 7; ++k) vk += gw.w[k] * bq[i + 1 + k];  // vnf[j0+i]
        float xc = 20.f * xacc;
        float tk = (xc + 1.f) * __expf(-xc);
        if (ch == 0 && i == 0) acc = (1.f - tk) * vk;
        else                   acc += (tp - tk) * (vp + vk) * 0.5f;
        tp = tk; vp = vk;
    }
    part[ch][xl] = acc;
    __syncthreads();

    if (ch == 0) {
        float r = part[0][xl] + part[1][xl] + part[2][xl] + part[3][xl];
        out[col] = fminf(fmaxf(r, 0.f), 1.f);
    }
}

// ---------------------------------------------------------------------------
extern "C" void kernel_launch(void* const* d_in, const int* in_sizes, int n_in,
                              void* d_out, int out_size, void* d_ws, size_t ws_size,
                              hipStream_t stream) {
    const float* d = (const float*)d_in[0];   // (4,1,128,128,128)
    const float* v = (const float*)d_in[1];   // (4,3,128,128,128)
    float* out = (float*)d_out;               // (4,1,128,128)

    GaussW gw;
    {
        double g[7], s = 0.0;
        for (int i = 0; i < 7; ++i) {
            double t = (i - 3) / 1.6;
            g[i] = exp(-t * t / 2.0);
            s += g[i];
        }
        for (int i = 0; i < 7; ++i) gw.w[i] = (float)(g[i] / s);
    }

    float* ws0 = (float*)d_ws;        // P = yx-smoothed d
    float* ws1 = ws0 + NVOX;          // Q = yx-smoothed |curl|

    // 1) fused: d yx-smooth (blocks 0-2047) + curl-on-the-fly yx-smooth (2048-4095)
    yx_curl_dual_kernel<<<2 * NB * DD * 4, 512, 0, stream>>>(d, ws0, v, ws1, gw);

    // 2) render: 4-way z-chunk parallel with LDS scan + on-the-fly z-smooth
    render_zs4_kernel<<<(NB * HH * WW) / 64, 256, 0, stream>>>(ws0, ws1, out, gw);
}